// Round 1
// baseline (275.465 us; speedup 1.0000x reference)
//
#include <hip/hip_runtime.h>

// ---------------------------------------------------------------------------
// memory_tree: fused bf16-MFMA MLP (13->300->600->100->13) + cosine-sim max.
// M=65536, B=2048, D=13. Padded dims: K1=32,N1=320; K2=320,N2=640; K3=640,
// N3=128; K4=128,N4=32(16 used). Zero-padded weights make pad lanes exact 0
// through relu/leaky, so no masking needed anywhere in the GEMMs.
// ---------------------------------------------------------------------------

typedef __bf16 bf16x8 __attribute__((ext_vector_type(8)));
typedef float f32x4 __attribute__((ext_vector_type(4)));

// ---- workspace layout (bytes) ---------------------------------------------
constexpr size_t OFF_W1B = 0;                    // [320][32]  bf16 = 20480
constexpr size_t OFF_W2B = 20480;                // [640][320] bf16 = 409600
constexpr size_t OFF_W3B = 430080;               // [128][640] bf16 = 163840
constexpr size_t OFF_W4B = 593920;               // [32][128]  bf16 = 8192
constexpr size_t OFF_B1  = 602112;               // [320] f32
constexpr size_t OFF_B2  = 603392;               // [640] f32
constexpr size_t OFF_B3  = 605952;               // [128] f32
constexpr size_t OFF_B4  = 606464;               // [32]  f32
constexpr size_t OFF_T2N = 606720;               // [2048][32] bf16 = 131072
constexpr size_t OFF_T1N = 737792;               // [65536][32] bf16 = 4194304
constexpr size_t OFF_PART= 4932096;              // [16][2048] f32 = 131072
// total need: 5063168 bytes (~4.83 MB)

__device__ __forceinline__ bf16x8 ld8(const __bf16* p) {
    return *reinterpret_cast<const bf16x8*>(p);
}
__device__ __forceinline__ f32x4 mfma16(bf16x8 a, bf16x8 b, f32x4 c) {
    return __builtin_amdgcn_mfma_f32_16x16x32_bf16(a, b, c, 0, 0, 0);
}
// XOR bank-swizzle: permute 16B slots within a row by row's low bits (T2 fix:
// row strides are 0 mod 128B -> unswizzled b128 reads would be 16-way conflicts)
template<int SW>
__device__ __forceinline__ int swcol(int row, int col) {
    return (((col >> 3) ^ (row & SW)) << 3) | (col & 7);
}

// ---------------------------------------------------------------------------
// prep: weights f32 -> zero-padded bf16, padded biases, t2n = normalize(value)
// ---------------------------------------------------------------------------
__global__ void prep_kernel(const float* __restrict__ W1, const float* __restrict__ b1,
                            const float* __restrict__ W2, const float* __restrict__ b2,
                            const float* __restrict__ W3, const float* __restrict__ b3,
                            const float* __restrict__ W4, const float* __restrict__ b4,
                            const float* __restrict__ value, char* __restrict__ ws) {
    __bf16* W1B = (__bf16*)(ws + OFF_W1B);
    __bf16* W2B = (__bf16*)(ws + OFF_W2B);
    __bf16* W3B = (__bf16*)(ws + OFF_W3B);
    __bf16* W4B = (__bf16*)(ws + OFF_W4B);
    float*  B1  = (float*)(ws + OFF_B1);
    float*  B2  = (float*)(ws + OFF_B2);
    float*  B3  = (float*)(ws + OFF_B3);
    float*  B4  = (float*)(ws + OFF_B4);
    __bf16* T2N = (__bf16*)(ws + OFF_T2N);

    int idx = blockIdx.x * 256 + threadIdx.x;
    if (idx < 10240) {                       // W1B [320][32]
        int n = idx >> 5, k = idx & 31;
        W1B[idx] = (__bf16)((n < 300 && k < 13) ? W1[n*13 + k] : 0.0f);
        return;
    }
    idx -= 10240;
    if (idx < 204800) {                      // W2B [640][320]
        int n = idx / 320, k = idx - n*320;
        W2B[idx] = (__bf16)((n < 600 && k < 300) ? W2[n*300 + k] : 0.0f);
        return;
    }
    idx -= 204800;
    if (idx < 81920) {                       // W3B [128][640]
        int n = idx / 640, k = idx - n*640;
        W3B[idx] = (__bf16)((n < 100 && k < 600) ? W3[n*600 + k] : 0.0f);
        return;
    }
    idx -= 81920;
    if (idx < 4096) {                        // W4B [32][128]
        int n = idx >> 7, k = idx & 127;
        W4B[idx] = (__bf16)((n < 13 && k < 100) ? W4[n*100 + k] : 0.0f);
        return;
    }
    idx -= 4096;
    if (idx < 320) { B1[idx] = idx < 300 ? b1[idx] : 0.0f; return; }
    idx -= 320;
    if (idx < 640) { B2[idx] = idx < 600 ? b2[idx] : 0.0f; return; }
    idx -= 640;
    if (idx < 128) { B3[idx] = idx < 100 ? b3[idx] : 0.0f; return; }
    idx -= 128;
    if (idx < 32)  { B4[idx] = idx < 13  ? b4[idx] : 0.0f; return; }
    idx -= 32;
    if (idx < 2048) {                        // t2n rows
        float v[13]; float s = 0.0f;
        #pragma unroll
        for (int k = 0; k < 13; k++) { v[k] = value[idx*13 + k]; s += v[k]*v[k]; }
        float inv = 1.0f / fmaxf(sqrtf(s), 1e-8f);
        #pragma unroll
        for (int k = 0; k < 13; k++) T2N[idx*32 + k] = (__bf16)(v[k] * inv);
        #pragma unroll
        for (int k = 13; k < 32; k++) T2N[idx*32 + k] = (__bf16)0.0f;
    }
}

// ---------------------------------------------------------------------------
// generic fused-layer GEMM: A(lds, [64][LDA] bf16 swizzled) x Bw(global [NP][KP]
// bf16, row=out-neuron) -> O(lds, [64][LDO] bf16 swizzled), bias+act fused.
// MW: waves split over M (4/MW m-tiles each); acc stays resident across K.
// A/B frags: 8 contiguous bf16 at k0=(lane>>4)*8 from row (lane&15) -- same
// k-pattern both operands, so any HW-internal k permutation cancels.
// ---------------------------------------------------------------------------
template<int KP, int NP, int MW, int MAXG, bool LEAKY, int SWA, int SWO, int LDA, int LDO>
__device__ __forceinline__ void layer(const __bf16* A, __bf16* O,
                                      const __bf16* __restrict__ Bw,
                                      const float* __restrict__ bias,
                                      int wave, int lane) {
    constexpr int NW = 8 / MW;        // n-way wave split
    constexpr int NG = NP / 16;       // 16-col n-tiles
    constexpr int MT = 4 / MW;        // 16-row m-tiles per wave
    const int lr = lane & 15, lg = lane >> 4;
    const int mw = wave % MW, nw = wave / MW;

    f32x4 acc[MAXG][MT] = {};
    for (int ks = 0; ks < KP/32; ks++) {
        const int k0 = ks*32 + lg*8;
        bf16x8 af[MT];
        #pragma unroll
        for (int mi = 0; mi < MT; mi++) {
            const int ar = (mw*MT + mi)*16 + lr;
            af[mi] = ld8(A + ar*LDA + (k0 ^ ((ar & SWA) << 3)));
        }
        #pragma unroll
        for (int j = 0; j < MAXG; j++) {
            const int g = nw + NW*j;
            if (g < NG) {
                bf16x8 bf = ld8(Bw + (g*16 + lr)*KP + k0);
                #pragma unroll
                for (int mi = 0; mi < MT; mi++)
                    acc[j][mi] = mfma16(af[mi], bf, acc[j][mi]);
            }
        }
    }
    #pragma unroll
    for (int j = 0; j < MAXG; j++) {
        const int g = nw + NW*j;
        if (g < NG) {
            const int col = g*16 + lr;
            const float bb = bias[col];
            #pragma unroll
            for (int mi = 0; mi < MT; mi++) {
                #pragma unroll
                for (int r = 0; r < 4; r++) {
                    const int row = (mw*MT + mi)*16 + lg*4 + r;  // verified C/D map
                    float v = acc[j][mi][r] + bb;
                    v = v > 0.0f ? v : (LEAKY ? 0.01f*v : 0.0f);
                    O[row*LDO + swcol<SWO>(row, col)] = (__bf16)v;
                }
            }
        }
    }
}

// ---------------------------------------------------------------------------
// fused MLP: 64 rows/block, all activations in LDS (144.25 KB -> 1 block/CU,
// 8 waves = 2/SIMD). Writes normalized t1n rows ([M][32] bf16, k>=13 zero).
// ---------------------------------------------------------------------------
__global__ __launch_bounds__(512, 2) void mlp_kernel(const float* __restrict__ mem,
                                                     char* __restrict__ ws) {
    __shared__ __bf16 xt[64*32];
    __shared__ __bf16 h1[64*320];
    __shared__ __bf16 h2[64*640];
    __shared__ __bf16 h3[64*128];
    __shared__ float  t1s[64*17];     // +1 pad: conflict-free row reads at norm

    const __bf16* W1B = (const __bf16*)(ws + OFF_W1B);
    const __bf16* W2B = (const __bf16*)(ws + OFF_W2B);
    const __bf16* W3B = (const __bf16*)(ws + OFF_W3B);
    const __bf16* W4B = (const __bf16*)(ws + OFF_W4B);
    const float*  B1  = (const float*)(ws + OFF_B1);
    const float*  B2  = (const float*)(ws + OFF_B2);
    const float*  B3  = (const float*)(ws + OFF_B3);
    const float*  B4  = (const float*)(ws + OFF_B4);
    __bf16* T1N = (__bf16*)(ws + OFF_T1N);

    const int tid = threadIdx.x;
    const int wave = tid >> 6, lane = tid & 63;
    const int lr = lane & 15, lg = lane >> 4;
    const int bm0 = blockIdx.x * 64;

    // stage x tile (zero-pad k 13..31)
    for (int i = tid; i < 64*32; i += 512) xt[i] = (__bf16)0.0f;
    __syncthreads();
    for (int i = tid; i < 64*13; i += 512) {
        int r = i / 13, c = i - r*13;
        xt[r*32 + swcol<3>(r, c)] = (__bf16)mem[(bm0 + r)*13 + c];
    }
    __syncthreads();

    layer< 32, 320, 1, 3, false, 3, 7,  32, 320>(xt, h1, W1B, B1, wave, lane);
    __syncthreads();
    layer<320, 640, 1, 5, true , 7, 7, 320, 640>(h1, h2, W2B, B2, wave, lane);
    __syncthreads();
    layer<640, 128, 2, 2, false, 7, 7, 640, 128>(h2, h3, W3B, B3, wave, lane);
    __syncthreads();

    // L4: 16 valid cols -> wave 0 only (16 MFMAs), f32 out + leaky into t1s
    if (wave == 0) {
        f32x4 acc[4] = {};
        for (int ks = 0; ks < 4; ks++) {
            const int k0 = ks*32 + lg*8;
            bf16x8 bf = ld8(W4B + lr*128 + k0);
            #pragma unroll
            for (int mi = 0; mi < 4; mi++) {
                const int ar = mi*16 + lr;
                bf16x8 af = ld8(h3 + ar*128 + (k0 ^ ((ar & 7) << 3)));
                acc[mi] = mfma16(af, bf, acc[mi]);
            }
        }
        #pragma unroll
        for (int mi = 0; mi < 4; mi++) {
            #pragma unroll
            for (int r = 0; r < 4; r++) {
                const int row = mi*16 + lg*4 + r;
                float v = acc[mi][r] + B4[lr];
                v = v > 0.0f ? v : 0.01f*v;
                t1s[row*17 + lr] = v;
            }
        }
    }
    __syncthreads();

    // normalize rows (torch clamp: /max(||t1||, 1e-8)) and emit bf16 [32]-padded
    if (tid < 64) {
        float s = 0.0f, v[13];
        #pragma unroll
        for (int k = 0; k < 13; k++) { v[k] = t1s[tid*17 + k]; s += v[k]*v[k]; }
        const float inv = 1.0f / fmaxf(sqrtf(s), 1e-8f);
        __bf16 o[32];
        #pragma unroll
        for (int k = 0; k < 13; k++) o[k] = (__bf16)(v[k] * inv);
        #pragma unroll
        for (int k = 13; k < 32; k++) o[k] = (__bf16)0.0f;
        bf16x8* dst = reinterpret_cast<bf16x8*>(T1N + (size_t)(bm0 + tid)*32);
        const bf16x8* src = reinterpret_cast<const bf16x8*>(o);
        #pragma unroll
        for (int i = 0; i < 4; i++) dst[i] = src[i];
    }
}

// ---------------------------------------------------------------------------
// sim: per wave one 16-b-row tile; iterate m-tiles (16-way grid m-split),
// MFMA dot (K=32 padded), running f32 max, shfl-xor reduce over 16 col-lanes.
// ---------------------------------------------------------------------------
__global__ __launch_bounds__(256) void sim_kernel(const char* __restrict__ ws_c,
                                                  float* __restrict__ part) {
    const char* ws = ws_c;
    const __bf16* T1N = (const __bf16*)(ws + OFF_T1N);
    const __bf16* T2N = (const __bf16*)(ws + OFF_T2N);
    const int wave = threadIdx.x >> 6, lane = threadIdx.x & 63;
    const int lr = lane & 15, lg = lane >> 4;
    const int bgroup = blockIdx.x & 31, ms = blockIdx.x >> 5;   // 32 x 16 grid
    const int btile = bgroup*4 + wave;                          // 0..127

    const bf16x8 af = ld8(T2N + (btile*16 + lr)*32 + lg*8);
    const f32x4 zero = {0.0f, 0.0f, 0.0f, 0.0f};
    f32x4 mx = {-3.0e38f, -3.0e38f, -3.0e38f, -3.0e38f};
    #pragma unroll 4
    for (int mt = ms; mt < 4096; mt += 16) {
        bf16x8 bf = ld8(T1N + ((size_t)mt*16 + lr)*32 + lg*8);
        f32x4 d = mfma16(af, bf, zero);
        #pragma unroll
        for (int r = 0; r < 4; r++) mx[r] = fmaxf(mx[r], d[r]);
    }
    #pragma unroll
    for (int off = 1; off <= 8; off <<= 1) {
        #pragma unroll
        for (int r = 0; r < 4; r++) mx[r] = fmaxf(mx[r], __shfl_xor(mx[r], off));
    }
    if (lr == 0) {
        #pragma unroll
        for (int r = 0; r < 4; r++)
            part[ms*2048 + btile*16 + lg*4 + r] = mx[r];
    }
}

__global__ void reduce_kernel(const float* __restrict__ part, float* __restrict__ out) {
    int b = blockIdx.x*256 + threadIdx.x;
    if (b < 2048) {
        float m = part[b];
        #pragma unroll
        for (int ms = 1; ms < 16; ms++) m = fmaxf(m, part[ms*2048 + b]);
        out[b] = 23.0f * m;
    }
}

// ---------------------------------------------------------------------------
extern "C" void kernel_launch(void* const* d_in, const int* in_sizes, int n_in,
                              void* d_out, int out_size, void* d_ws, size_t ws_size,
                              hipStream_t stream) {
    const float* memory = (const float*)d_in[0];
    const float* value  = (const float*)d_in[1];
    const float* W1 = (const float*)d_in[2]; const float* b1 = (const float*)d_in[3];
    const float* W2 = (const float*)d_in[4]; const float* b2 = (const float*)d_in[5];
    const float* W3 = (const float*)d_in[6]; const float* b3 = (const float*)d_in[7];
    const float* W4 = (const float*)d_in[8]; const float* b4 = (const float*)d_in[9];
    char* ws = (char*)d_ws;
    float* part = (float*)(ws + OFF_PART);
    float* out = (float*)d_out;

    // 304224 prep items
    prep_kernel<<<1189, 256, 0, stream>>>(W1, b1, W2, b2, W3, b3, W4, b4, value, ws);
    mlp_kernel<<<1024, 512, 0, stream>>>(memory, ws);
    sim_kernel<<<512, 256, 0, stream>>>(ws, part);
    reduce_kernel<<<8, 256, 0, stream>>>(part, out);
}

// Round 2
// 204.752 us; speedup vs baseline: 1.3454x; 1.3454x over previous
//
#include <hip/hip_runtime.h>

// ---------------------------------------------------------------------------
// memory_tree: fused bf16-MFMA MLP (13->300->600->100->13) + cosine-sim max.
// R1: fuse L2+L3 with chunked h2 (double-buffered 128-col chunks) so LDS
// drops 148K->76K => 2 blocks/CU (4 waves/SIMD) for latency hiding.
// sim: 2 b-tiles per wave (halves T1N traffic, 2 MFMA per load).
// ---------------------------------------------------------------------------

typedef __bf16 bf16x8 __attribute__((ext_vector_type(8)));
typedef float f32x4 __attribute__((ext_vector_type(4)));

// ---- workspace layout (bytes) ---------------------------------------------
constexpr size_t OFF_W1B = 0;                    // [320][32]  bf16 = 20480
constexpr size_t OFF_W2B = 20480;                // [640][320] bf16 = 409600
constexpr size_t OFF_W3B = 430080;               // [128][640] bf16 = 163840
constexpr size_t OFF_W4B = 593920;               // [32][128]  bf16 = 8192
constexpr size_t OFF_B1  = 602112;               // [320] f32
constexpr size_t OFF_B2  = 603392;               // [640] f32
constexpr size_t OFF_B3  = 605952;               // [128] f32
constexpr size_t OFF_B4  = 606464;               // [32]  f32
constexpr size_t OFF_T2N = 606720;               // [2048][32] bf16 = 131072
constexpr size_t OFF_T1N = 737792;               // [65536][32] bf16 = 4194304
constexpr size_t OFF_PART= 4932096;              // [32][2048] f32 = 262144
// total: 5194240 bytes (~4.95 MB)

__device__ __forceinline__ bf16x8 ld8(const __bf16* p) {
    return *reinterpret_cast<const bf16x8*>(p);
}
__device__ __forceinline__ f32x4 mfma16(bf16x8 a, bf16x8 b, f32x4 c) {
    return __builtin_amdgcn_mfma_f32_16x16x32_bf16(a, b, c, 0, 0, 0);
}
// XOR bank-swizzle on 16B slots (row strides are 0 mod 128B otherwise)
template<int SW>
__device__ __forceinline__ int swcol(int row, int col) {
    return (((col >> 3) ^ (row & SW)) << 3) | (col & 7);
}

// ---------------------------------------------------------------------------
// prep: weights f32 -> zero-padded bf16, padded biases, t2n = normalize(value)
// ---------------------------------------------------------------------------
__global__ void prep_kernel(const float* __restrict__ W1, const float* __restrict__ b1,
                            const float* __restrict__ W2, const float* __restrict__ b2,
                            const float* __restrict__ W3, const float* __restrict__ b3,
                            const float* __restrict__ W4, const float* __restrict__ b4,
                            const float* __restrict__ value, char* __restrict__ ws) {
    __bf16* W1B = (__bf16*)(ws + OFF_W1B);
    __bf16* W2B = (__bf16*)(ws + OFF_W2B);
    __bf16* W3B = (__bf16*)(ws + OFF_W3B);
    __bf16* W4B = (__bf16*)(ws + OFF_W4B);
    float*  B1  = (float*)(ws + OFF_B1);
    float*  B2  = (float*)(ws + OFF_B2);
    float*  B3  = (float*)(ws + OFF_B3);
    float*  B4  = (float*)(ws + OFF_B4);
    __bf16* T2N = (__bf16*)(ws + OFF_T2N);

    int idx = blockIdx.x * 256 + threadIdx.x;
    if (idx < 10240) {                       // W1B [320][32]
        int n = idx >> 5, k = idx & 31;
        W1B[idx] = (__bf16)((n < 300 && k < 13) ? W1[n*13 + k] : 0.0f);
        return;
    }
    idx -= 10240;
    if (idx < 204800) {                      // W2B [640][320]
        int n = idx / 320, k = idx - n*320;
        W2B[idx] = (__bf16)((n < 600 && k < 300) ? W2[n*300 + k] : 0.0f);
        return;
    }
    idx -= 204800;
    if (idx < 81920) {                       // W3B [128][640]
        int n = idx / 640, k = idx - n*640;
        W3B[idx] = (__bf16)((n < 100 && k < 600) ? W3[n*600 + k] : 0.0f);
        return;
    }
    idx -= 81920;
    if (idx < 4096) {                        // W4B [32][128]
        int n = idx >> 7, k = idx & 127;
        W4B[idx] = (__bf16)((n < 13 && k < 100) ? W4[n*100 + k] : 0.0f);
        return;
    }
    idx -= 4096;
    if (idx < 320) { B1[idx] = idx < 300 ? b1[idx] : 0.0f; return; }
    idx -= 320;
    if (idx < 640) { B2[idx] = idx < 600 ? b2[idx] : 0.0f; return; }
    idx -= 640;
    if (idx < 128) { B3[idx] = idx < 100 ? b3[idx] : 0.0f; return; }
    idx -= 128;
    if (idx < 32)  { B4[idx] = idx < 13  ? b4[idx] : 0.0f; return; }
    idx -= 32;
    if (idx < 2048) {                        // t2n rows
        float v[13]; float s = 0.0f;
        #pragma unroll
        for (int k = 0; k < 13; k++) { v[k] = value[idx*13 + k]; s += v[k]*v[k]; }
        float inv = 1.0f / fmaxf(sqrtf(s), 1e-8f);
        #pragma unroll
        for (int k = 0; k < 13; k++) T2N[idx*32 + k] = (__bf16)(v[k] * inv);
        #pragma unroll
        for (int k = 13; k < 32; k++) T2N[idx*32 + k] = (__bf16)0.0f;
    }
}

// ---------------------------------------------------------------------------
// layer template (used for L1 only): A(lds) x Bw(global) -> O(lds), bias+act.
// ---------------------------------------------------------------------------
template<int KP, int NP, int MW, int MAXG, bool LEAKY, int SWA, int SWO, int LDA, int LDO>
__device__ __forceinline__ void layer(const __bf16* A, __bf16* O,
                                      const __bf16* __restrict__ Bw,
                                      const float* __restrict__ bias,
                                      int wave, int lane) {
    constexpr int NW = 8 / MW;
    constexpr int NG = NP / 16;
    constexpr int MT = 4 / MW;
    const int lr = lane & 15, lg = lane >> 4;
    const int mw = wave % MW, nw = wave / MW;

    f32x4 acc[MAXG][MT] = {};
    for (int ks = 0; ks < KP/32; ks++) {
        const int k0 = ks*32 + lg*8;
        bf16x8 af[MT];
        #pragma unroll
        for (int mi = 0; mi < MT; mi++) {
            const int ar = (mw*MT + mi)*16 + lr;
            af[mi] = ld8(A + ar*LDA + (k0 ^ ((ar & SWA) << 3)));
        }
        #pragma unroll
        for (int j = 0; j < MAXG; j++) {
            const int g = nw + NW*j;
            if (g < NG) {
                bf16x8 bf = ld8(Bw + (g*16 + lr)*KP + k0);
                #pragma unroll
                for (int mi = 0; mi < MT; mi++)
                    acc[j][mi] = mfma16(af[mi], bf, acc[j][mi]);
            }
        }
    }
    #pragma unroll
    for (int j = 0; j < MAXG; j++) {
        const int g = nw + NW*j;
        if (g < NG) {
            const int col = g*16 + lr;
            const float bb = bias[col];
            #pragma unroll
            for (int mi = 0; mi < MT; mi++) {
                #pragma unroll
                for (int r = 0; r < 4; r++) {
                    const int row = (mw*MT + mi)*16 + lg*4 + r;
                    float v = acc[j][mi][r] + bb;
                    v = v > 0.0f ? v : (LEAKY ? 0.01f*v : 0.0f);
                    O[row*LDO + swcol<SWO>(row, col)] = (__bf16)v;
                }
            }
        }
    }
}

// ---------------------------------------------------------------------------
// fused MLP: 64 rows/block. LDS 76KB => 2 blocks/CU (4 waves/SIMD).
//   xt  @0      [64][32]  bf16  (dead after L1)
//   h1  @4096   [64][320] bf16  (dead after last L2 chunk)
//   h2c @45056  2 x [64][128] bf16 (double-buffered chunk)
//   h3  @4096   [64][128] bf16  (aliases h1)
//   t1s @20480  [64][17]  f32   (aliases h1 tail)
// L2+L3 fused: 5 chunks of 128 h2-cols; acc3 register-resident.
// ---------------------------------------------------------------------------
__global__ __launch_bounds__(512, 4) void mlp_kernel(const float* __restrict__ mem,
                                                     char* __restrict__ ws) {
    __shared__ char smem[77824];
    __bf16* xt  = (__bf16*)(smem);
    __bf16* h1  = (__bf16*)(smem + 4096);
    __bf16* h2c = (__bf16*)(smem + 45056);
    __bf16* h3  = (__bf16*)(smem + 4096);
    float*  t1s = (float*)(smem + 20480);

    const __bf16* W1B = (const __bf16*)(ws + OFF_W1B);
    const __bf16* W2B = (const __bf16*)(ws + OFF_W2B);
    const __bf16* W3B = (const __bf16*)(ws + OFF_W3B);
    const __bf16* W4B = (const __bf16*)(ws + OFF_W4B);
    const float*  B1  = (const float*)(ws + OFF_B1);
    const float*  B2  = (const float*)(ws + OFF_B2);
    const float*  B3  = (const float*)(ws + OFF_B3);
    const float*  B4  = (const float*)(ws + OFF_B4);
    __bf16* T1N = (__bf16*)(ws + OFF_T1N);

    const int tid = threadIdx.x;
    const int wave = tid >> 6, lane = tid & 63;
    const int lr = lane & 15, lg = lane >> 4;
    const int bm0 = blockIdx.x * 64;

    // stage x tile (zero-pad k 13..31)
    for (int i = tid; i < 64*32; i += 512) xt[i] = (__bf16)0.0f;
    __syncthreads();
    for (int i = tid; i < 64*13; i += 512) {
        int r = i / 13, c = i - r*13;
        xt[r*32 + swcol<3>(r, c)] = (__bf16)mem[(bm0 + r)*13 + c];
    }
    __syncthreads();

    layer< 32, 320, 1, 3, false, 3, 7,  32, 320>(xt, h1, W1B, B1, wave, lane);
    __syncthreads();

    // ---- fused L2+L3 over 5 chunks of 128 h2-cols ----
    f32x4 acc3[4] = {};

    auto l2chunk = [&](int c, int buf) {
        f32x4 acc2[4] = {};
        const int nc0 = c * 128;
        const __bf16* brow = W2B + (nc0 + wave*16 + lr) * 320;
        #pragma unroll
        for (int ks = 0; ks < 10; ks++) {
            const int k0 = ks*32 + lg*8;
            bf16x8 bfv = ld8(brow + k0);
            #pragma unroll
            for (int mi = 0; mi < 4; mi++) {
                const int ar = mi*16 + lr;
                bf16x8 af = ld8(h1 + ar*320 + (k0 ^ ((ar & 7) << 3)));
                acc2[mi] = mfma16(af, bfv, acc2[mi]);
            }
        }
        const int col = wave*16 + lr;
        const float bb = B2[nc0 + col];
        __bf16* dst = h2c + buf*8192;
        #pragma unroll
        for (int mi = 0; mi < 4; mi++) {
            #pragma unroll
            for (int r = 0; r < 4; r++) {
                const int row = mi*16 + lg*4 + r;
                float v = acc2[mi][r] + bb;
                v = v > 0.0f ? v : 0.01f*v;
                dst[row*128 + swcol<7>(row, col)] = (__bf16)v;
            }
        }
    };
    auto l3chunk = [&](int c, int buf) {
        const int nc0 = c * 128;
        const __bf16* brow = W3B + (wave*16 + lr) * 640 + nc0;
        const __bf16* src = h2c + buf*8192;
        #pragma unroll
        for (int ks = 0; ks < 4; ks++) {
            const int k0 = ks*32 + lg*8;
            bf16x8 bfv = ld8(brow + k0);
            #pragma unroll
            for (int mi = 0; mi < 4; mi++) {
                const int ar = mi*16 + lr;
                bf16x8 af = ld8(src + ar*128 + (k0 ^ ((ar & 7) << 3)));
                acc3[mi] = mfma16(af, bfv, acc3[mi]);
            }
        }
    };

    l2chunk(0, 0);
    __syncthreads();
    for (int c = 0; c < 5; c++) {
        if (c < 4) l2chunk(c + 1, (c + 1) & 1);
        l3chunk(c, c & 1);
        __syncthreads();
    }

    // L3 epilogue: bias+relu -> h3 (aliases h1; all h1 reads are done)
    {
        const int col = wave*16 + lr;
        const float bb = B3[col];
        #pragma unroll
        for (int mi = 0; mi < 4; mi++) {
            #pragma unroll
            for (int r = 0; r < 4; r++) {
                const int row = mi*16 + lg*4 + r;
                float v = acc3[mi][r] + bb;
                v = v > 0.0f ? v : 0.0f;
                h3[row*128 + swcol<7>(row, col)] = (__bf16)v;
            }
        }
    }
    __syncthreads();

    // L4: 16 valid cols; waves 0..3 take one m-tile each
    if (wave < 4) {
        f32x4 a4 = {0.0f, 0.0f, 0.0f, 0.0f};
        #pragma unroll
        for (int ks = 0; ks < 4; ks++) {
            const int k0 = ks*32 + lg*8;
            bf16x8 bfv = ld8(W4B + lr*128 + k0);
            const int ar = wave*16 + lr;
            bf16x8 af = ld8(h3 + ar*128 + (k0 ^ ((ar & 7) << 3)));
            a4 = mfma16(af, bfv, a4);
        }
        #pragma unroll
        for (int r = 0; r < 4; r++) {
            const int row = wave*16 + lg*4 + r;
            float v = a4[r] + B4[lr];
            v = v > 0.0f ? v : 0.01f*v;
            t1s[row*17 + lr] = v;
        }
    }
    __syncthreads();

    // normalize rows (torch clamp: /max(||t1||,1e-8)) -> T1N [32]-padded bf16
    if (tid < 64) {
        float s = 0.0f, v[13];
        #pragma unroll
        for (int k = 0; k < 13; k++) { v[k] = t1s[tid*17 + k]; s += v[k]*v[k]; }
        const float inv = 1.0f / fmaxf(sqrtf(s), 1e-8f);
        __bf16 o[32];
        #pragma unroll
        for (int k = 0; k < 13; k++) o[k] = (__bf16)(v[k] * inv);
        #pragma unroll
        for (int k = 13; k < 32; k++) o[k] = (__bf16)0.0f;
        bf16x8* dst = reinterpret_cast<bf16x8*>(T1N + (size_t)(bm0 + tid)*32);
        const bf16x8* src = reinterpret_cast<const bf16x8*>(o);
        #pragma unroll
        for (int i = 0; i < 4; i++) dst[i] = src[i];
    }
}

// ---------------------------------------------------------------------------
// sim: per wave 2 b-tiles (af reused), 32-way m-split; running f32 max,
// shfl-xor reduce over the 16 col-lanes.
// ---------------------------------------------------------------------------
__global__ __launch_bounds__(256) void sim_kernel(const char* __restrict__ ws_c,
                                                  float* __restrict__ part) {
    const char* ws = ws_c;
    const __bf16* T1N = (const __bf16*)(ws + OFF_T1N);
    const __bf16* T2N = (const __bf16*)(ws + OFF_T2N);
    const int wave = threadIdx.x >> 6, lane = threadIdx.x & 63;
    const int lr = lane & 15, lg = lane >> 4;
    const int bgroup = blockIdx.x & 15, ms = blockIdx.x >> 4;   // 16 x 32 grid
    const int bt0 = bgroup*8 + wave*2;                          // 2 b-tiles/wave

    bf16x8 af[2];
    #pragma unroll
    for (int v = 0; v < 2; v++)
        af[v] = ld8(T2N + ((bt0 + v)*16 + lr)*32 + lg*8);

    const f32x4 zero = {0.0f, 0.0f, 0.0f, 0.0f};
    f32x4 mx[2];
    #pragma unroll
    for (int v = 0; v < 2; v++) mx[v] = {-3.0e38f, -3.0e38f, -3.0e38f, -3.0e38f};

    #pragma unroll 4
    for (int mt = ms; mt < 4096; mt += 32) {
        bf16x8 bfv = ld8(T1N + ((size_t)mt*16 + lr)*32 + lg*8);
        #pragma unroll
        for (int v = 0; v < 2; v++) {
            f32x4 d = mfma16(af[v], bfv, zero);
            #pragma unroll
            for (int r = 0; r < 4; r++) mx[v][r] = fmaxf(mx[v][r], d[r]);
        }
    }
    #pragma unroll
    for (int off = 1; off <= 8; off <<= 1) {
        #pragma unroll
        for (int v = 0; v < 2; v++)
            #pragma unroll
            for (int r = 0; r < 4; r++) mx[v][r] = fmaxf(mx[v][r], __shfl_xor(mx[v][r], off));
    }
    if (lr == 0) {
        #pragma unroll
        for (int v = 0; v < 2; v++)
            #pragma unroll
            for (int r = 0; r < 4; r++)
                part[ms*2048 + (bt0 + v)*16 + lg*4 + r] = mx[v][r];
    }
}

__global__ void reduce_kernel(const float* __restrict__ part, float* __restrict__ out) {
    int b = blockIdx.x*256 + threadIdx.x;
    if (b < 2048) {
        float m = part[b];
        #pragma unroll
        for (int ms = 1; ms < 32; ms++) m = fmaxf(m, part[ms*2048 + b]);
        out[b] = 23.0f * m;
    }
}

// ---------------------------------------------------------------------------
extern "C" void kernel_launch(void* const* d_in, const int* in_sizes, int n_in,
                              void* d_out, int out_size, void* d_ws, size_t ws_size,
                              hipStream_t stream) {
    const float* memory = (const float*)d_in[0];
    const float* value  = (const float*)d_in[1];
    const float* W1 = (const float*)d_in[2]; const float* b1 = (const float*)d_in[3];
    const float* W2 = (const float*)d_in[4]; const float* b2 = (const float*)d_in[5];
    const float* W3 = (const float*)d_in[6]; const float* b3 = (const float*)d_in[7];
    const float* W4 = (const float*)d_in[8]; const float* b4 = (const float*)d_in[9];
    char* ws = (char*)d_ws;
    float* part = (float*)(ws + OFF_PART);
    float* out = (float*)d_out;

    prep_kernel<<<1189, 256, 0, stream>>>(W1, b1, W2, b2, W3, b3, W4, b4, value, ws);
    mlp_kernel<<<1024, 512, 0, stream>>>(memory, ws);
    sim_kernel<<<512, 256, 0, stream>>>(ws, part);
    reduce_kernel<<<8, 256, 0, stream>>>(part, out);
}

// Round 3
// 193.792 us; speedup vs baseline: 1.4214x; 1.0566x over previous
//
#include <hip/hip_runtime.h>

// ---------------------------------------------------------------------------
// memory_tree: fused bf16-MFMA MLP (13->300->600->100->13) + cosine-sim max.
// R3: L2/L3 on 32x32x16 MFMA with producer/consumer wave split and 2-n-tile
// af reuse => LDS A-traffic per block 2.2MB -> 560KB. Weights prepacked in
// MFMA fragment order (coalesced 1KB B-streams). sim on 32x32 tiles.
// ---------------------------------------------------------------------------

typedef __bf16 bf16x8 __attribute__((ext_vector_type(8)));
typedef float f32x4 __attribute__((ext_vector_type(4)));
typedef float f32x16 __attribute__((ext_vector_type(16)));

// ---- workspace layout (bytes) ---------------------------------------------
constexpr size_t OFF_W1B = 0;                    // [320][32] bf16 (row layout)
constexpr size_t OFF_W2B = 20480;                // frag-order [20][20][64][8] bf16
constexpr size_t OFF_W3B = 430080;               // frag-order [4][40][64][8] bf16
constexpr size_t OFF_W4B = 593920;               // [32][128] bf16 (row layout)
constexpr size_t OFF_B1  = 602112;               // [320] f32
constexpr size_t OFF_B2  = 603392;               // [640] f32
constexpr size_t OFF_B3  = 605952;               // [128] f32
constexpr size_t OFF_B4  = 606464;               // [32]  f32
constexpr size_t OFF_T2N = 606720;               // [2048][32] bf16
constexpr size_t OFF_T1N = 737792;               // [65536][32] bf16
constexpr size_t OFF_PART= 4932096;              // [32][2048] f32
// total: 5194240 bytes

__device__ __forceinline__ bf16x8 ld8(const __bf16* p) {
    return *reinterpret_cast<const bf16x8*>(p);
}
__device__ __forceinline__ f32x4 mfma16(bf16x8 a, bf16x8 b, f32x4 c) {
    return __builtin_amdgcn_mfma_f32_16x16x32_bf16(a, b, c, 0, 0, 0);
}
__device__ __forceinline__ f32x16 mfma32(bf16x8 a, bf16x8 b, f32x16 c) {
    return __builtin_amdgcn_mfma_f32_32x32x16_bf16(a, b, c, 0, 0, 0);
}
// XOR bank-swizzle on 16B slots (row strides are 0 mod 128B otherwise)
template<int SW>
__device__ __forceinline__ int swcol(int row, int col) {
    return (((col >> 3) ^ (row & SW)) << 3) | (col & 7);
}

// ---------------------------------------------------------------------------
// prep: weights -> bf16 (W2/W3 in MFMA fragment order), biases, t2n
// ---------------------------------------------------------------------------
__global__ void prep_kernel(const float* __restrict__ W1, const float* __restrict__ b1,
                            const float* __restrict__ W2, const float* __restrict__ b2,
                            const float* __restrict__ W3, const float* __restrict__ b3,
                            const float* __restrict__ W4, const float* __restrict__ b4,
                            const float* __restrict__ value, char* __restrict__ ws) {
    __bf16* W1B = (__bf16*)(ws + OFF_W1B);
    __bf16* W2B = (__bf16*)(ws + OFF_W2B);
    __bf16* W3B = (__bf16*)(ws + OFF_W3B);
    __bf16* W4B = (__bf16*)(ws + OFF_W4B);
    float*  B1  = (float*)(ws + OFF_B1);
    float*  B2  = (float*)(ws + OFF_B2);
    float*  B3  = (float*)(ws + OFF_B3);
    float*  B4  = (float*)(ws + OFF_B4);
    __bf16* T2N = (__bf16*)(ws + OFF_T2N);

    int idx = blockIdx.x * 256 + threadIdx.x;
    if (idx < 10240) {                       // W1B [320][32] row layout
        int n = idx >> 5, k = idx & 31;
        W1B[idx] = (__bf16)((n < 300 && k < 13) ? W1[n*13 + k] : 0.0f);
        return;
    }
    idx -= 10240;
    if (idx < 204800) {                      // W2B frag order [nt<20][ks<20][lane][8]
        int e = idx & 7, lane = (idx >> 3) & 63, r = idx >> 9;
        int ks = r % 20, nt = r / 20;
        int n = nt*32 + (lane & 31);
        int k = ks*16 + (lane >> 5)*8 + e;
        W2B[idx] = (__bf16)((n < 600 && k < 300) ? W2[n*300 + k] : 0.0f);
        return;
    }
    idx -= 204800;
    if (idx < 81920) {                       // W3B frag order [nt<4][ks<40][lane][8]
        int e = idx & 7, lane = (idx >> 3) & 63, r = idx >> 9;
        int ks = r % 40, nt = r / 40;
        int n = nt*32 + (lane & 31);
        int k = ks*16 + (lane >> 5)*8 + e;
        W3B[idx] = (__bf16)((n < 100 && k < 600) ? W3[n*600 + k] : 0.0f);
        return;
    }
    idx -= 81920;
    if (idx < 4096) {                        // W4B [32][128] row layout
        int n = idx >> 7, k = idx & 127;
        W4B[idx] = (__bf16)((n < 13 && k < 100) ? W4[n*100 + k] : 0.0f);
        return;
    }
    idx -= 4096;
    if (idx < 320) { B1[idx] = idx < 300 ? b1[idx] : 0.0f; return; }
    idx -= 320;
    if (idx < 640) { B2[idx] = idx < 600 ? b2[idx] : 0.0f; return; }
    idx -= 640;
    if (idx < 128) { B3[idx] = idx < 100 ? b3[idx] : 0.0f; return; }
    idx -= 128;
    if (idx < 32)  { B4[idx] = idx < 13  ? b4[idx] : 0.0f; return; }
    idx -= 32;
    if (idx < 2048) {                        // t2n rows
        float v[13]; float s = 0.0f;
        #pragma unroll
        for (int k = 0; k < 13; k++) { v[k] = value[idx*13 + k]; s += v[k]*v[k]; }
        float inv = 1.0f / fmaxf(sqrtf(s), 1e-8f);
        #pragma unroll
        for (int k = 0; k < 13; k++) T2N[idx*32 + k] = (__bf16)(v[k] * inv);
        #pragma unroll
        for (int k = 13; k < 32; k++) T2N[idx*32 + k] = (__bf16)0.0f;
    }
}

// ---------------------------------------------------------------------------
// L1 layer (16x16 path, small): A(lds) x Bw(global rows) -> O(lds)
// ---------------------------------------------------------------------------
template<int KP, int NP, int MAXG, int SWA, int SWO, int LDA, int LDO>
__device__ __forceinline__ void layer1(const __bf16* A, __bf16* O,
                                       const __bf16* __restrict__ Bw,
                                       const float* __restrict__ bias,
                                       int wave, int lane) {
    constexpr int NG = NP / 16;
    const int lr = lane & 15, lg = lane >> 4;

    f32x4 acc[MAXG][4] = {};
    for (int ks = 0; ks < KP/32; ks++) {
        const int k0 = ks*32 + lg*8;
        bf16x8 af[4];
        #pragma unroll
        for (int mi = 0; mi < 4; mi++) {
            const int ar = mi*16 + lr;
            af[mi] = ld8(A + ar*LDA + (k0 ^ ((ar & SWA) << 3)));
        }
        #pragma unroll
        for (int j = 0; j < MAXG; j++) {
            const int g = wave + 8*j;
            if (g < NG) {
                bf16x8 bf = ld8(Bw + (g*16 + lr)*KP + k0);
                #pragma unroll
                for (int mi = 0; mi < 4; mi++)
                    acc[j][mi] = mfma16(af[mi], bf, acc[j][mi]);
            }
        }
    }
    #pragma unroll
    for (int j = 0; j < MAXG; j++) {
        const int g = wave + 8*j;
        if (g < NG) {
            const int col = g*16 + lr;
            const float bb = bias[col];
            #pragma unroll
            for (int mi = 0; mi < 4; mi++) {
                #pragma unroll
                for (int r = 0; r < 4; r++) {
                    const int row = mi*16 + lg*4 + r;
                    float v = acc[j][mi][r] + bb;
                    v = v > 0.0f ? v : 0.0f;
                    O[row*LDO + swcol<SWO>(row, col)] = (__bf16)v;
                }
            }
        }
    }
}

// ---------------------------------------------------------------------------
// fused MLP: 64 rows/block (2 m-tiles of 32), 8 waves, LDS 76KB (2 blk/CU).
// Waves 0-3: produce h2 chunks (128 cols, 32x32 MFMA, 2 n-tiles/wave).
// Waves 4-7: consume chunks into register-resident L3 acc (2 n-tiles/wave).
// ---------------------------------------------------------------------------
__global__ __launch_bounds__(512, 4) void mlp_kernel(const float* __restrict__ mem,
                                                     char* __restrict__ ws) {
    __shared__ char smem[77824];
    __bf16* xt  = (__bf16*)(smem);            // [64][32]   4KB
    __bf16* h1  = (__bf16*)(smem + 4096);     // [64][320] 40KB
    __bf16* h2c = (__bf16*)(smem + 45056);    // 2 x [64][128] 32KB
    __bf16* h3  = (__bf16*)(smem + 4096);     // [64][128] 16KB (aliases h1)
    float*  t1s = (float*)(smem + 20480);     // [64][17] f32

    const __bf16* W1B = (const __bf16*)(ws + OFF_W1B);
    const __bf16* W2B = (const __bf16*)(ws + OFF_W2B);
    const __bf16* W3B = (const __bf16*)(ws + OFF_W3B);
    const __bf16* W4B = (const __bf16*)(ws + OFF_W4B);
    const float*  B1  = (const float*)(ws + OFF_B1);
    const float*  B2  = (const float*)(ws + OFF_B2);
    const float*  B3  = (const float*)(ws + OFF_B3);
    const float*  B4  = (const float*)(ws + OFF_B4);
    __bf16* T1N = (__bf16*)(ws + OFF_T1N);

    const int tid = threadIdx.x;
    const int wave = tid >> 6, lane = tid & 63;
    const int lr = lane & 15, lg = lane >> 4;
    const int l31 = lane & 31, l5 = lane >> 5;
    const int bm0 = blockIdx.x * 64;

    // stage x tile (zero-pad k 13..31)
    for (int i = tid; i < 64*32; i += 512) xt[i] = (__bf16)0.0f;
    __syncthreads();
    for (int i = tid; i < 64*13; i += 512) {
        int r = i / 13, c = i - r*13;
        xt[r*32 + swcol<3>(r, c)] = (__bf16)mem[(bm0 + r)*13 + c];
    }
    __syncthreads();

    layer1<32, 320, 3, 3, 7, 32, 320>(xt, h1, W1B, B1, wave, lane);
    __syncthreads();

    // ---- fused L2+L3, 5 chunks of 128 h2-cols, producer/consumer split ----
    const int mw = (wave & 3) & 1, ns = (wave & 3) >> 1;   // role-local coords
    const int arow2 = mw*32 + l31;                          // A row (both roles)
    const int rsw = arow2 & 7;

    f32x16 acc3a = {}, acc3b = {};   // consumer L3 accumulators (resident)

    auto produce = [&](int c, int buf) {
        f32x16 a0 = {}, a1 = {};
        const __bf16* ap = h1 + arow2*320;
        const int nt0 = c*4 + ns*2;
        const __bf16* bp0 = W2B + ((nt0*20)*64 + lane)*8;
        const __bf16* bp1 = W2B + (((nt0+1)*20)*64 + lane)*8;
        #pragma unroll 5
        for (int ks = 0; ks < 20; ks++) {
            const int k0 = ks*16 + l5*8;
            bf16x8 af = ld8(ap + (((k0 >> 3) ^ rsw) << 3));
            bf16x8 b0 = ld8(bp0 + ks*512);
            bf16x8 b1 = ld8(bp1 + ks*512);
            a0 = mfma32(af, b0, a0);
            a1 = mfma32(af, b1, a1);
        }
        __bf16* dst = h2c + buf*8192;
        const int c0 = ns*64 + l31, c1 = c0 + 32;
        const float bb0 = B2[c*128 + c0], bb1 = B2[c*128 + c1];
        #pragma unroll
        for (int reg = 0; reg < 16; reg++) {
            const int rl = mw*32 + (reg & 3) + 8*(reg >> 2) + 4*l5;
            float v0 = a0[reg] + bb0; v0 = v0 > 0.0f ? v0 : 0.01f*v0;
            float v1 = a1[reg] + bb1; v1 = v1 > 0.0f ? v1 : 0.01f*v1;
            dst[rl*128 + swcol<7>(rl, c0)] = (__bf16)v0;
            dst[rl*128 + swcol<7>(rl, c1)] = (__bf16)v1;
        }
    };

    if (wave < 4) produce(0, 0);
    __syncthreads();

    for (int c = 0; c < 5; c++) {
        if (wave < 4) {
            if (c < 4) produce(c + 1, (c + 1) & 1);
        } else {
            const __bf16* src = h2c + (c & 1)*8192 + arow2*128;
            const __bf16* bp0 = W3B + (((ns*2)*40 + c*8)*64 + lane)*8;
            const __bf16* bp1 = W3B + (((ns*2+1)*40 + c*8)*64 + lane)*8;
            #pragma unroll
            for (int ks = 0; ks < 8; ks++) {
                const int k0 = ks*16 + l5*8;
                bf16x8 af = ld8(src + (((k0 >> 3) ^ rsw) << 3));
                bf16x8 b0 = ld8(bp0 + ks*512);
                bf16x8 b1 = ld8(bp1 + ks*512);
                acc3a = mfma32(af, b0, acc3a);
                acc3b = mfma32(af, b1, acc3b);
            }
        }
        __syncthreads();
    }

    // consumer epilogue: bias+relu -> h3 (h1 fully dead now)
    if (wave >= 4) {
        const int c0 = ns*64 + l31, c1 = c0 + 32;
        const float bb0 = B3[c0], bb1 = B3[c1];
        #pragma unroll
        for (int reg = 0; reg < 16; reg++) {
            const int rl = mw*32 + (reg & 3) + 8*(reg >> 2) + 4*l5;
            float v0 = acc3a[reg] + bb0; v0 = v0 > 0.0f ? v0 : 0.0f;
            float v1 = acc3b[reg] + bb1; v1 = v1 > 0.0f ? v1 : 0.0f;
            h3[rl*128 + swcol<7>(rl, c0)] = (__bf16)v0;
            h3[rl*128 + swcol<7>(rl, c1)] = (__bf16)v1;
        }
    }
    __syncthreads();

    // L4: 16 valid cols; waves 0..3 take one 16-row m-tile each (16x16 path)
    if (wave < 4) {
        f32x4 a4 = {0.0f, 0.0f, 0.0f, 0.0f};
        #pragma unroll
        for (int ks = 0; ks < 4; ks++) {
            const int k0 = ks*32 + lg*8;
            bf16x8 bfv = ld8(W4B + lr*128 + k0);
            const int ar = wave*16 + lr;
            bf16x8 af = ld8(h3 + ar*128 + (k0 ^ ((ar & 7) << 3)));
            a4 = mfma16(af, bfv, a4);
        }
        #pragma unroll
        for (int r = 0; r < 4; r++) {
            const int row = wave*16 + lg*4 + r;
            float v = a4[r] + B4[lr];
            v = v > 0.0f ? v : 0.01f*v;
            t1s[row*17 + lr] = v;
        }
    }
    __syncthreads();

    // normalize rows -> T1N [32]-padded bf16
    if (tid < 64) {
        float s = 0.0f, v[13];
        #pragma unroll
        for (int k = 0; k < 13; k++) { v[k] = t1s[tid*17 + k]; s += v[k]*v[k]; }
        const float inv = 1.0f / fmaxf(sqrtf(s), 1e-8f);
        __bf16 o[32];
        #pragma unroll
        for (int k = 0; k < 13; k++) o[k] = (__bf16)(v[k] * inv);
        #pragma unroll
        for (int k = 13; k < 32; k++) o[k] = (__bf16)0.0f;
        bf16x8* dst = reinterpret_cast<bf16x8*>(T1N + (size_t)(bm0 + tid)*32);
        const bf16x8* src = reinterpret_cast<const bf16x8*>(o);
        #pragma unroll
        for (int i = 0; i < 4; i++) dst[i] = src[i];
    }
}

// ---------------------------------------------------------------------------
// sim: 32x32 tiles. Wave owns 32 b-rows; streams 64 T1N m-tiles (32-way
// m-split); K=32 via 2 chained MFMAs; running max in 16 f32; shfl reduce
// over the 32 m-lanes.
// ---------------------------------------------------------------------------
__global__ __launch_bounds__(256) void sim_kernel(const char* __restrict__ ws_c,
                                                  float* __restrict__ part) {
    const char* ws = ws_c;
    const __bf16* T1N = (const __bf16*)(ws + OFF_T1N);
    const __bf16* T2N = (const __bf16*)(ws + OFF_T2N);
    const int wave = threadIdx.x >> 6, lane = threadIdx.x & 63;
    const int l31 = lane & 31, l5 = lane >> 5;
    const int bgroup = blockIdx.x & 15, ms = blockIdx.x >> 4;   // 16 x 32 grid
    const int b0 = (bgroup*4 + wave) * 32;

    const bf16x8 af0 = ld8(T2N + (b0 + l31)*32 + l5*8);
    const bf16x8 af1 = ld8(T2N + (b0 + l31)*32 + 16 + l5*8);
    const f32x16 zero = {};
    f32x16 mx;
    #pragma unroll
    for (int r = 0; r < 16; r++) mx[r] = -3.0e38f;

    #pragma unroll 4
    for (int mt = ms; mt < 2048; mt += 32) {
        const __bf16* p = T1N + ((size_t)mt*32 + l31)*32 + l5*8;
        bf16x8 bf0 = ld8(p);
        bf16x8 bf1 = ld8(p + 16);
        f32x16 d = mfma32(af1, bf1, mfma32(af0, bf0, zero));
        #pragma unroll
        for (int r = 0; r < 16; r++) mx[r] = fmaxf(mx[r], d[r]);
    }
    #pragma unroll
    for (int off = 1; off <= 16; off <<= 1) {
        #pragma unroll
        for (int r = 0; r < 16; r++) mx[r] = fmaxf(mx[r], __shfl_xor(mx[r], off));
    }
    if (l31 == 0) {
        #pragma unroll
        for (int reg = 0; reg < 16; reg++)
            part[ms*2048 + b0 + (reg & 3) + 8*(reg >> 2) + 4*l5] = mx[reg];
    }
}

__global__ void reduce_kernel(const float* __restrict__ part, float* __restrict__ out) {
    int b = blockIdx.x*256 + threadIdx.x;
    if (b < 2048) {
        float m = part[b];
        #pragma unroll
        for (int ms = 1; ms < 32; ms++) m = fmaxf(m, part[ms*2048 + b]);
        out[b] = 23.0f * m;
    }
}

// ---------------------------------------------------------------------------
extern "C" void kernel_launch(void* const* d_in, const int* in_sizes, int n_in,
                              void* d_out, int out_size, void* d_ws, size_t ws_size,
                              hipStream_t stream) {
    const float* memory = (const float*)d_in[0];
    const float* value  = (const float*)d_in[1];
    const float* W1 = (const float*)d_in[2]; const float* b1 = (const float*)d_in[3];
    const float* W2 = (const float*)d_in[4]; const float* b2 = (const float*)d_in[5];
    const float* W3 = (const float*)d_in[6]; const float* b3 = (const float*)d_in[7];
    const float* W4 = (const float*)d_in[8]; const float* b4 = (const float*)d_in[9];
    char* ws = (char*)d_ws;
    float* part = (float*)(ws + OFF_PART);
    float* out = (float*)d_out;

    prep_kernel<<<1189, 256, 0, stream>>>(W1, b1, W2, b2, W3, b3, W4, b4, value, ws);
    mlp_kernel<<<1024, 512, 0, stream>>>(memory, ws);
    sim_kernel<<<512, 256, 0, stream>>>(ws, part);
    reduce_kernel<<<8, 256, 0, stream>>>(part, out);
}

// Round 4
// 172.326 us; speedup vs baseline: 1.5985x; 1.1246x over previous
//
#include <hip/hip_runtime.h>

// ---------------------------------------------------------------------------
// memory_tree: fused bf16-MFMA MLP (13->300->600->100->13) + cosine-sim max.
// R4: unified phases (no producer/consumer split -- R3's split made acc3+a0/a1
// coexist per-thread at VGPR_Count=64 => f32x16 spill, 30MB scratch writes).
// All 8 waves: per chunk c do L3(c) then L2(c+1), 1 barrier/chunk. Wave =
// (mw=wave&1, nw=wave>>1): one 32x32 n-tile per phase; acc3 persistent (16),
// acc2 transient 2-chain (32) => ~85 VGPRs, no spill.
// ---------------------------------------------------------------------------

typedef __bf16 bf16x8 __attribute__((ext_vector_type(8)));
typedef float f32x4 __attribute__((ext_vector_type(4)));
typedef float f32x16 __attribute__((ext_vector_type(16)));

// ---- workspace layout (bytes) ---------------------------------------------
constexpr size_t OFF_W1B = 0;                    // [320][32] bf16 (row layout)
constexpr size_t OFF_W2B = 20480;                // frag-order [20][20][64][8] bf16
constexpr size_t OFF_W3B = 430080;               // frag-order [4][40][64][8] bf16
constexpr size_t OFF_W4B = 593920;               // [32][128] bf16 (row layout)
constexpr size_t OFF_B1  = 602112;               // [320] f32
constexpr size_t OFF_B2  = 603392;               // [640] f32
constexpr size_t OFF_B3  = 605952;               // [128] f32
constexpr size_t OFF_B4  = 606464;               // [32]  f32
constexpr size_t OFF_T2N = 606720;               // [2048][32] bf16
constexpr size_t OFF_T1N = 737792;               // [65536][32] bf16
constexpr size_t OFF_PART= 4932096;              // [32][2048] f32
// total: 5194240 bytes

__device__ __forceinline__ bf16x8 ld8(const __bf16* p) {
    return *reinterpret_cast<const bf16x8*>(p);
}
__device__ __forceinline__ f32x4 mfma16(bf16x8 a, bf16x8 b, f32x4 c) {
    return __builtin_amdgcn_mfma_f32_16x16x32_bf16(a, b, c, 0, 0, 0);
}
__device__ __forceinline__ f32x16 mfma32(bf16x8 a, bf16x8 b, f32x16 c) {
    return __builtin_amdgcn_mfma_f32_32x32x16_bf16(a, b, c, 0, 0, 0);
}
// XOR bank-swizzle on 16B slots (row strides are 0 mod 128B otherwise)
template<int SW>
__device__ __forceinline__ int swcol(int row, int col) {
    return (((col >> 3) ^ (row & SW)) << 3) | (col & 7);
}

// ---------------------------------------------------------------------------
// prep: weights -> bf16 (W2/W3 in MFMA fragment order), biases, t2n
// ---------------------------------------------------------------------------
__global__ void prep_kernel(const float* __restrict__ W1, const float* __restrict__ b1,
                            const float* __restrict__ W2, const float* __restrict__ b2,
                            const float* __restrict__ W3, const float* __restrict__ b3,
                            const float* __restrict__ W4, const float* __restrict__ b4,
                            const float* __restrict__ value, char* __restrict__ ws) {
    __bf16* W1B = (__bf16*)(ws + OFF_W1B);
    __bf16* W2B = (__bf16*)(ws + OFF_W2B);
    __bf16* W3B = (__bf16*)(ws + OFF_W3B);
    __bf16* W4B = (__bf16*)(ws + OFF_W4B);
    float*  B1  = (float*)(ws + OFF_B1);
    float*  B2  = (float*)(ws + OFF_B2);
    float*  B3  = (float*)(ws + OFF_B3);
    float*  B4  = (float*)(ws + OFF_B4);
    __bf16* T2N = (__bf16*)(ws + OFF_T2N);

    int idx = blockIdx.x * 256 + threadIdx.x;
    if (idx < 10240) {                       // W1B [320][32] row layout
        int n = idx >> 5, k = idx & 31;
        W1B[idx] = (__bf16)((n < 300 && k < 13) ? W1[n*13 + k] : 0.0f);
        return;
    }
    idx -= 10240;
    if (idx < 204800) {                      // W2B frag order [nt<20][ks<20][lane][8]
        int e = idx & 7, lane = (idx >> 3) & 63, r = idx >> 9;
        int ks = r % 20, nt = r / 20;
        int n = nt*32 + (lane & 31);
        int k = ks*16 + (lane >> 5)*8 + e;
        W2B[idx] = (__bf16)((n < 600 && k < 300) ? W2[n*300 + k] : 0.0f);
        return;
    }
    idx -= 204800;
    if (idx < 81920) {                       // W3B frag order [nt<4][ks<40][lane][8]
        int e = idx & 7, lane = (idx >> 3) & 63, r = idx >> 9;
        int ks = r % 40, nt = r / 40;
        int n = nt*32 + (lane & 31);
        int k = ks*16 + (lane >> 5)*8 + e;
        W3B[idx] = (__bf16)((n < 100 && k < 600) ? W3[n*600 + k] : 0.0f);
        return;
    }
    idx -= 81920;
    if (idx < 4096) {                        // W4B [32][128] row layout
        int n = idx >> 7, k = idx & 127;
        W4B[idx] = (__bf16)((n < 13 && k < 100) ? W4[n*100 + k] : 0.0f);
        return;
    }
    idx -= 4096;
    if (idx < 320) { B1[idx] = idx < 300 ? b1[idx] : 0.0f; return; }
    idx -= 320;
    if (idx < 640) { B2[idx] = idx < 600 ? b2[idx] : 0.0f; return; }
    idx -= 640;
    if (idx < 128) { B3[idx] = idx < 100 ? b3[idx] : 0.0f; return; }
    idx -= 128;
    if (idx < 32)  { B4[idx] = idx < 13  ? b4[idx] : 0.0f; return; }
    idx -= 32;
    if (idx < 2048) {                        // t2n rows
        float v[13]; float s = 0.0f;
        #pragma unroll
        for (int k = 0; k < 13; k++) { v[k] = value[idx*13 + k]; s += v[k]*v[k]; }
        float inv = 1.0f / fmaxf(sqrtf(s), 1e-8f);
        #pragma unroll
        for (int k = 0; k < 13; k++) T2N[idx*32 + k] = (__bf16)(v[k] * inv);
        #pragma unroll
        for (int k = 13; k < 32; k++) T2N[idx*32 + k] = (__bf16)0.0f;
    }
}

// ---------------------------------------------------------------------------
// L1 layer (16x16 path, small): A(lds) x Bw(global rows) -> O(lds)
// ---------------------------------------------------------------------------
template<int KP, int NP, int MAXG, int SWA, int SWO, int LDA, int LDO>
__device__ __forceinline__ void layer1(const __bf16* A, __bf16* O,
                                       const __bf16* __restrict__ Bw,
                                       const float* __restrict__ bias,
                                       int wave, int lane) {
    constexpr int NG = NP / 16;
    const int lr = lane & 15, lg = lane >> 4;

    f32x4 acc[MAXG][4] = {};
    for (int ks = 0; ks < KP/32; ks++) {
        const int k0 = ks*32 + lg*8;
        bf16x8 af[4];
        #pragma unroll
        for (int mi = 0; mi < 4; mi++) {
            const int ar = mi*16 + lr;
            af[mi] = ld8(A + ar*LDA + (k0 ^ ((ar & SWA) << 3)));
        }
        #pragma unroll
        for (int j = 0; j < MAXG; j++) {
            const int g = wave + 8*j;
            if (g < NG) {
                bf16x8 bf = ld8(Bw + (g*16 + lr)*KP + k0);
                #pragma unroll
                for (int mi = 0; mi < 4; mi++)
                    acc[j][mi] = mfma16(af[mi], bf, acc[j][mi]);
            }
        }
    }
    #pragma unroll
    for (int j = 0; j < MAXG; j++) {
        const int g = wave + 8*j;
        if (g < NG) {
            const int col = g*16 + lr;
            const float bb = bias[col];
            #pragma unroll
            for (int mi = 0; mi < 4; mi++) {
                #pragma unroll
                for (int r = 0; r < 4; r++) {
                    const int row = mi*16 + lg*4 + r;
                    float v = acc[j][mi][r] + bb;
                    v = v > 0.0f ? v : 0.0f;
                    O[row*LDO + swcol<SWO>(row, col)] = (__bf16)v;
                }
            }
        }
    }
}

// ---------------------------------------------------------------------------
// fused MLP: 64 rows/block (2 m-tiles of 32), 8 waves, LDS 76KB (2 blk/CU).
// Unified phases: per chunk, every wave does L3(c) then L2(c+1); wave =
// (mw=wave&1, nw=wave>>1) owns one 32x32 n-tile per phase.
// ---------------------------------------------------------------------------
__global__ __launch_bounds__(512, 4) void mlp_kernel(const float* __restrict__ mem,
                                                     char* __restrict__ ws) {
    __shared__ char smem[77824];
    __bf16* xt  = (__bf16*)(smem);            // [64][32]   4KB
    __bf16* h1  = (__bf16*)(smem + 4096);     // [64][320] 40KB
    __bf16* h2c = (__bf16*)(smem + 45056);    // 2 x [64][128] 32KB
    __bf16* h3  = (__bf16*)(smem + 4096);     // [64][128] 16KB (aliases h1)
    float*  t1s = (float*)(smem + 20480);     // [64][17] f32 (aliases h1 tail)

    const __bf16* W1B = (const __bf16*)(ws + OFF_W1B);
    const __bf16* W2B = (const __bf16*)(ws + OFF_W2B);
    const __bf16* W3B = (const __bf16*)(ws + OFF_W3B);
    const __bf16* W4B = (const __bf16*)(ws + OFF_W4B);
    const float*  B1  = (const float*)(ws + OFF_B1);
    const float*  B2  = (const float*)(ws + OFF_B2);
    const float*  B3  = (const float*)(ws + OFF_B3);
    const float*  B4  = (const float*)(ws + OFF_B4);
    __bf16* T1N = (__bf16*)(ws + OFF_T1N);

    const int tid = threadIdx.x;
    const int wave = tid >> 6, lane = tid & 63;
    const int lr = lane & 15, lg = lane >> 4;
    const int l31 = lane & 31, l5 = lane >> 5;
    const int bm0 = blockIdx.x * 64;

    // stage x tile (zero-pad k 13..31)
    for (int i = tid; i < 64*32; i += 512) xt[i] = (__bf16)0.0f;
    __syncthreads();
    for (int i = tid; i < 64*13; i += 512) {
        int r = i / 13, c = i - r*13;
        xt[r*32 + swcol<3>(r, c)] = (__bf16)mem[(bm0 + r)*13 + c];
    }
    __syncthreads();

    layer1<32, 320, 3, 3, 7, 32, 320>(xt, h1, W1B, B1, wave, lane);
    __syncthreads();

    // ---- fused L2+L3, 5 chunks of 128 h2-cols, unified waves ----
    const int mw = wave & 1, nw = wave >> 1;     // mw: m-half, nw: n-tile 0..3
    const int arow = mw*32 + l31;                // A row for both L2 and L3
    const int rsw = arow & 7;

    f32x16 acc3 = {};                            // persistent L3 accumulator

    auto l2chunk = [&](int c, int buf) {
        f32x16 e0 = {}, e1 = {};                 // 2-chain ILP
        const __bf16* ap = h1 + arow*320;
        const int nt = c*4 + nw;
        const __bf16* bp = W2B + ((nt*20)*64 + lane)*8;
        #pragma unroll
        for (int ks = 0; ks < 20; ks += 2) {
            const int k0a = ks*16 + l5*8;
            const int k0b = k0a + 16;
            bf16x8 afa = ld8(ap + (((k0a >> 3) ^ rsw) << 3) + (k0a & 7));
            bf16x8 afb = ld8(ap + (((k0b >> 3) ^ rsw) << 3) + (k0b & 7));
            bf16x8 ba = ld8(bp + ks*512);
            bf16x8 bb = ld8(bp + ks*512 + 512);
            e0 = mfma32(afa, ba, e0);
            e1 = mfma32(afb, bb, e1);
        }
        __bf16* dst = h2c + buf*8192;
        const int col = nw*32 + l31;             // 0..127 within chunk
        const float bb2 = B2[c*128 + col];
        #pragma unroll
        for (int reg = 0; reg < 16; reg++) {
            const int rl = mw*32 + (reg & 3) + 8*(reg >> 2) + 4*l5;
            float v = e0[reg] + e1[reg] + bb2;
            v = v > 0.0f ? v : 0.01f*v;
            dst[rl*128 + swcol<7>(rl, col)] = (__bf16)v;
        }
    };
    auto l3chunk = [&](int c) {
        const __bf16* src = h2c + (c & 1)*8192 + arow*128;
        const __bf16* bp = W3B + ((nw*40 + c*8)*64 + lane)*8;
        #pragma unroll
        for (int ks = 0; ks < 8; ks++) {
            const int k0 = ks*16 + l5*8;
            bf16x8 af = ld8(src + (((k0 >> 3) ^ rsw) << 3));
            bf16x8 bf = ld8(bp + ks*512);
            acc3 = mfma32(af, bf, acc3);
        }
    };

    l2chunk(0, 0);
    __syncthreads();
    for (int c = 0; c < 5; c++) {
        l3chunk(c);
        if (c < 4) l2chunk(c + 1, (c + 1) & 1);
        __syncthreads();
    }

    // L3 epilogue: bias+relu -> h3 (h1 fully dead after l2chunk(4))
    {
        const int col = nw*32 + l31;
        const float bb3 = B3[col];
        #pragma unroll
        for (int reg = 0; reg < 16; reg++) {
            const int rl = mw*32 + (reg & 3) + 8*(reg >> 2) + 4*l5;
            float v = acc3[reg] + bb3;
            v = v > 0.0f ? v : 0.0f;
            h3[rl*128 + swcol<7>(rl, col)] = (__bf16)v;
        }
    }
    __syncthreads();

    // L4: 16 valid cols; waves 0..3 take one 16-row m-tile each (16x16 path)
    if (wave < 4) {
        f32x4 a4 = {0.0f, 0.0f, 0.0f, 0.0f};
        #pragma unroll
        for (int ks = 0; ks < 4; ks++) {
            const int k0 = ks*32 + lg*8;
            bf16x8 bfv = ld8(W4B + lr*128 + k0);
            const int ar = wave*16 + lr;
            bf16x8 af = ld8(h3 + ar*128 + (k0 ^ ((ar & 7) << 3)));
            a4 = mfma16(af, bfv, a4);
        }
        #pragma unroll
        for (int r = 0; r < 4; r++) {
            const int row = wave*16 + lg*4 + r;
            float v = a4[r] + B4[lr];
            v = v > 0.0f ? v : 0.01f*v;
            t1s[row*17 + lr] = v;
        }
    }
    __syncthreads();

    // normalize rows -> T1N [32]-padded bf16
    if (tid < 64) {
        float s = 0.0f, v[13];
        #pragma unroll
        for (int k = 0; k < 13; k++) { v[k] = t1s[tid*17 + k]; s += v[k]*v[k]; }
        const float inv = 1.0f / fmaxf(sqrtf(s), 1e-8f);
        __bf16 o[32];
        #pragma unroll
        for (int k = 0; k < 13; k++) o[k] = (__bf16)(v[k] * inv);
        #pragma unroll
        for (int k = 13; k < 32; k++) o[k] = (__bf16)0.0f;
        bf16x8* dst = reinterpret_cast<bf16x8*>(T1N + (size_t)(bm0 + tid)*32);
        const bf16x8* src = reinterpret_cast<const bf16x8*>(o);
        #pragma unroll
        for (int i = 0; i < 4; i++) dst[i] = src[i];
    }
}

// ---------------------------------------------------------------------------
// sim: 32x32 tiles. Wave owns 32 b-rows; streams 64 T1N m-tiles (32-way
// m-split); K=32 via 2 chained MFMAs; running max; shfl reduce over 32 lanes.
// ---------------------------------------------------------------------------
__global__ __launch_bounds__(256) void sim_kernel(const char* __restrict__ ws_c,
                                                  float* __restrict__ part) {
    const char* ws = ws_c;
    const __bf16* T1N = (const __bf16*)(ws + OFF_T1N);
    const __bf16* T2N = (const __bf16*)(ws + OFF_T2N);
    const int wave = threadIdx.x >> 6, lane = threadIdx.x & 63;
    const int l31 = lane & 31, l5 = lane >> 5;
    const int bgroup = blockIdx.x & 15, ms = blockIdx.x >> 4;   // 16 x 32 grid
    const int b0 = (bgroup*4 + wave) * 32;

    const bf16x8 af0 = ld8(T2N + (b0 + l31)*32 + l5*8);
    const bf16x8 af1 = ld8(T2N + (b0 + l31)*32 + 16 + l5*8);
    const f32x16 zero = {};
    f32x16 mx;
    #pragma unroll
    for (int r = 0; r < 16; r++) mx[r] = -3.0e38f;

    #pragma unroll 4
    for (int mt = ms; mt < 2048; mt += 32) {
        const __bf16* p = T1N + ((size_t)mt*32 + l31)*32 + l5*8;
        bf16x8 bf0 = ld8(p);
        bf16x8 bf1 = ld8(p + 16);
        f32x16 d = mfma32(af1, bf1, mfma32(af0, bf0, zero));
        #pragma unroll
        for (int r = 0; r < 16; r++) mx[r] = fmaxf(mx[r], d[r]);
    }
    #pragma unroll
    for (int off = 1; off <= 16; off <<= 1) {
        #pragma unroll
        for (int r = 0; r < 16; r++) mx[r] = fmaxf(mx[r], __shfl_xor(mx[r], off));
    }
    if (l31 == 0) {
        #pragma unroll
        for (int reg = 0; reg < 16; reg++)
            part[ms*2048 + b0 + (reg & 3) + 8*(reg >> 2) + 4*l5] = mx[reg];
    }
}

__global__ void reduce_kernel(const float* __restrict__ part, float* __restrict__ out) {
    int b = blockIdx.x*256 + threadIdx.x;
    if (b < 2048) {
        float m = part[b];
        #pragma unroll
        for (int ms = 1; ms < 32; ms++) m = fmaxf(m, part[ms*2048 + b]);
        out[b] = 23.0f * m;
    }
}

// ---------------------------------------------------------------------------
extern "C" void kernel_launch(void* const* d_in, const int* in_sizes, int n_in,
                              void* d_out, int out_size, void* d_ws, size_t ws_size,
                              hipStream_t stream) {
    const float* memory = (const float*)d_in[0];
    const float* value  = (const float*)d_in[1];
    const float* W1 = (const float*)d_in[2]; const float* b1 = (const float*)d_in[3];
    const float* W2 = (const float*)d_in[4]; const float* b2 = (const float*)d_in[5];
    const float* W3 = (const float*)d_in[6]; const float* b3 = (const float*)d_in[7];
    const float* W4 = (const float*)d_in[8]; const float* b4 = (const float*)d_in[9];
    char* ws = (char*)d_ws;
    float* part = (float*)(ws + OFF_PART);
    float* out = (float*)d_out;

    prep_kernel<<<1189, 256, 0, stream>>>(W1, b1, W2, b2, W3, b3, W4, b4, value, ws);
    mlp_kernel<<<1024, 512, 0, stream>>>(memory, ws);
    sim_kernel<<<512, 256, 0, stream>>>(ws, part);
    reduce_kernel<<<8, 256, 0, stream>>>(part, out);
}

// Round 5
// 170.014 us; speedup vs baseline: 1.6202x; 1.0136x over previous
//
#include <hip/hip_runtime.h>

// ---------------------------------------------------------------------------
// memory_tree: fused bf16-MFMA MLP (13->300->600->100->13) + cosine-sim max.
// R5: __launch_bounds__(512,2) -- this toolchain treats arg2 as CUDA-style
// min-BLOCKS/CU (evidence: (512,4)=>VGPR capped 64 = 512-pool/8waves;
// (512,2)=>cap 128). R4's 53MB WRITE_SIZE was f32x16 accumulator spill under
// the 64-reg cap. sim: 64-way m-split + 2-tile max3 step.
// ---------------------------------------------------------------------------

typedef __bf16 bf16x8 __attribute__((ext_vector_type(8)));
typedef float f32x4 __attribute__((ext_vector_type(4)));
typedef float f32x16 __attribute__((ext_vector_type(16)));

// ---- workspace layout (bytes) ---------------------------------------------
constexpr size_t OFF_W1B = 0;                    // [320][32] bf16 (row layout)
constexpr size_t OFF_W2B = 20480;                // frag-order [20][20][64][8] bf16
constexpr size_t OFF_W3B = 430080;               // frag-order [4][40][64][8] bf16
constexpr size_t OFF_W4B = 593920;               // [32][128] bf16 (row layout)
constexpr size_t OFF_B1  = 602112;               // [320] f32
constexpr size_t OFF_B2  = 603392;               // [640] f32
constexpr size_t OFF_B3  = 605952;               // [128] f32
constexpr size_t OFF_B4  = 606464;               // [32]  f32
constexpr size_t OFF_T2N = 606720;               // [2048][32] bf16
constexpr size_t OFF_T1N = 737792;               // [65536][32] bf16
constexpr size_t OFF_PART= 4932096;              // [64][2048] f32 = 524288
// total: 5456384 bytes (~5.2 MB)

__device__ __forceinline__ bf16x8 ld8(const __bf16* p) {
    return *reinterpret_cast<const bf16x8*>(p);
}
__device__ __forceinline__ f32x4 mfma16(bf16x8 a, bf16x8 b, f32x4 c) {
    return __builtin_amdgcn_mfma_f32_16x16x32_bf16(a, b, c, 0, 0, 0);
}
__device__ __forceinline__ f32x16 mfma32(bf16x8 a, bf16x8 b, f32x16 c) {
    return __builtin_amdgcn_mfma_f32_32x32x16_bf16(a, b, c, 0, 0, 0);
}
// XOR bank-swizzle on 16B slots (row strides are 0 mod 128B otherwise)
template<int SW>
__device__ __forceinline__ int swcol(int row, int col) {
    return (((col >> 3) ^ (row & SW)) << 3) | (col & 7);
}

// ---------------------------------------------------------------------------
// prep: weights -> bf16 (W2/W3 in MFMA fragment order), biases, t2n
// ---------------------------------------------------------------------------
__global__ void prep_kernel(const float* __restrict__ W1, const float* __restrict__ b1,
                            const float* __restrict__ W2, const float* __restrict__ b2,
                            const float* __restrict__ W3, const float* __restrict__ b3,
                            const float* __restrict__ W4, const float* __restrict__ b4,
                            const float* __restrict__ value, char* __restrict__ ws) {
    __bf16* W1B = (__bf16*)(ws + OFF_W1B);
    __bf16* W2B = (__bf16*)(ws + OFF_W2B);
    __bf16* W3B = (__bf16*)(ws + OFF_W3B);
    __bf16* W4B = (__bf16*)(ws + OFF_W4B);
    float*  B1  = (float*)(ws + OFF_B1);
    float*  B2  = (float*)(ws + OFF_B2);
    float*  B3  = (float*)(ws + OFF_B3);
    float*  B4  = (float*)(ws + OFF_B4);
    __bf16* T2N = (__bf16*)(ws + OFF_T2N);

    int idx = blockIdx.x * 256 + threadIdx.x;
    if (idx < 10240) {                       // W1B [320][32] row layout
        int n = idx >> 5, k = idx & 31;
        W1B[idx] = (__bf16)((n < 300 && k < 13) ? W1[n*13 + k] : 0.0f);
        return;
    }
    idx -= 10240;
    if (idx < 204800) {                      // W2B frag order [nt<20][ks<20][lane][8]
        int e = idx & 7, lane = (idx >> 3) & 63, r = idx >> 9;
        int ks = r % 20, nt = r / 20;
        int n = nt*32 + (lane & 31);
        int k = ks*16 + (lane >> 5)*8 + e;
        W2B[idx] = (__bf16)((n < 600 && k < 300) ? W2[n*300 + k] : 0.0f);
        return;
    }
    idx -= 204800;
    if (idx < 81920) {                       // W3B frag order [nt<4][ks<40][lane][8]
        int e = idx & 7, lane = (idx >> 3) & 63, r = idx >> 9;
        int ks = r % 40, nt = r / 40;
        int n = nt*32 + (lane & 31);
        int k = ks*16 + (lane >> 5)*8 + e;
        W3B[idx] = (__bf16)((n < 100 && k < 600) ? W3[n*600 + k] : 0.0f);
        return;
    }
    idx -= 81920;
    if (idx < 4096) {                        // W4B [32][128] row layout
        int n = idx >> 7, k = idx & 127;
        W4B[idx] = (__bf16)((n < 13 && k < 100) ? W4[n*100 + k] : 0.0f);
        return;
    }
    idx -= 4096;
    if (idx < 320) { B1[idx] = idx < 300 ? b1[idx] : 0.0f; return; }
    idx -= 320;
    if (idx < 640) { B2[idx] = idx < 600 ? b2[idx] : 0.0f; return; }
    idx -= 640;
    if (idx < 128) { B3[idx] = idx < 100 ? b3[idx] : 0.0f; return; }
    idx -= 128;
    if (idx < 32)  { B4[idx] = idx < 13  ? b4[idx] : 0.0f; return; }
    idx -= 32;
    if (idx < 2048) {                        // t2n rows
        float v[13]; float s = 0.0f;
        #pragma unroll
        for (int k = 0; k < 13; k++) { v[k] = value[idx*13 + k]; s += v[k]*v[k]; }
        float inv = 1.0f / fmaxf(sqrtf(s), 1e-8f);
        #pragma unroll
        for (int k = 0; k < 13; k++) T2N[idx*32 + k] = (__bf16)(v[k] * inv);
        #pragma unroll
        for (int k = 13; k < 32; k++) T2N[idx*32 + k] = (__bf16)0.0f;
    }
}

// ---------------------------------------------------------------------------
// L1 layer (16x16 path, small): A(lds) x Bw(global rows) -> O(lds)
// ---------------------------------------------------------------------------
template<int KP, int NP, int MAXG, int SWA, int SWO, int LDA, int LDO>
__device__ __forceinline__ void layer1(const __bf16* A, __bf16* O,
                                       const __bf16* __restrict__ Bw,
                                       const float* __restrict__ bias,
                                       int wave, int lane) {
    constexpr int NG = NP / 16;
    const int lr = lane & 15, lg = lane >> 4;

    f32x4 acc[MAXG][4] = {};
    for (int ks = 0; ks < KP/32; ks++) {
        const int k0 = ks*32 + lg*8;
        bf16x8 af[4];
        #pragma unroll
        for (int mi = 0; mi < 4; mi++) {
            const int ar = mi*16 + lr;
            af[mi] = ld8(A + ar*LDA + (k0 ^ ((ar & SWA) << 3)));
        }
        #pragma unroll
        for (int j = 0; j < MAXG; j++) {
            const int g = wave + 8*j;
            if (g < NG) {
                bf16x8 bf = ld8(Bw + (g*16 + lr)*KP + k0);
                #pragma unroll
                for (int mi = 0; mi < 4; mi++)
                    acc[j][mi] = mfma16(af[mi], bf, acc[j][mi]);
            }
        }
    }
    #pragma unroll
    for (int j = 0; j < MAXG; j++) {
        const int g = wave + 8*j;
        if (g < NG) {
            const int col = g*16 + lr;
            const float bb = bias[col];
            #pragma unroll
            for (int mi = 0; mi < 4; mi++) {
                #pragma unroll
                for (int r = 0; r < 4; r++) {
                    const int row = mi*16 + lg*4 + r;
                    float v = acc[j][mi][r] + bb;
                    v = v > 0.0f ? v : 0.0f;
                    O[row*LDO + swcol<SWO>(row, col)] = (__bf16)v;
                }
            }
        }
    }
}

// ---------------------------------------------------------------------------
// fused MLP: 64 rows/block (2 m-tiles of 32), 8 waves, LDS 76KB (2 blk/CU).
// Unified phases: per chunk, every wave does L3(c) then L2(c+1); wave =
// (mw=wave&1, nw=wave>>1) owns one 32x32 n-tile per phase.
// NOTE launch_bounds 2nd arg: CUDA-style min-blocks/CU on this toolchain.
// (512,4) capped VGPR at 64 -> f32x16 spill (53MB scratch writes, R4).
// ---------------------------------------------------------------------------
__global__ __launch_bounds__(512, 2) void mlp_kernel(const float* __restrict__ mem,
                                                     char* __restrict__ ws) {
    __shared__ char smem[77824];
    __bf16* xt  = (__bf16*)(smem);            // [64][32]   4KB
    __bf16* h1  = (__bf16*)(smem + 4096);     // [64][320] 40KB
    __bf16* h2c = (__bf16*)(smem + 45056);    // 2 x [64][128] 32KB
    __bf16* h3  = (__bf16*)(smem + 4096);     // [64][128] 16KB (aliases h1)
    float*  t1s = (float*)(smem + 20480);     // [64][17] f32 (aliases h1 tail)

    const __bf16* W1B = (const __bf16*)(ws + OFF_W1B);
    const __bf16* W2B = (const __bf16*)(ws + OFF_W2B);
    const __bf16* W3B = (const __bf16*)(ws + OFF_W3B);
    const __bf16* W4B = (const __bf16*)(ws + OFF_W4B);
    const float*  B1  = (const float*)(ws + OFF_B1);
    const float*  B2  = (const float*)(ws + OFF_B2);
    const float*  B3  = (const float*)(ws + OFF_B3);
    const float*  B4  = (const float*)(ws + OFF_B4);
    __bf16* T1N = (__bf16*)(ws + OFF_T1N);

    const int tid = threadIdx.x;
    const int wave = tid >> 6, lane = tid & 63;
    const int lr = lane & 15, lg = lane >> 4;
    const int l31 = lane & 31, l5 = lane >> 5;
    const int bm0 = blockIdx.x * 64;

    // stage x tile (zero-pad k 13..31)
    for (int i = tid; i < 64*32; i += 512) xt[i] = (__bf16)0.0f;
    __syncthreads();
    for (int i = tid; i < 64*13; i += 512) {
        int r = i / 13, c = i - r*13;
        xt[r*32 + swcol<3>(r, c)] = (__bf16)mem[(bm0 + r)*13 + c];
    }
    __syncthreads();

    layer1<32, 320, 3, 3, 7, 32, 320>(xt, h1, W1B, B1, wave, lane);
    __syncthreads();

    // ---- fused L2+L3, 5 chunks of 128 h2-cols, unified waves ----
    const int mw = wave & 1, nw = wave >> 1;     // mw: m-half, nw: n-tile 0..3
    const int arow = mw*32 + l31;                // A row for both L2 and L3
    const int rsw = arow & 7;

    f32x16 acc3 = {};                            // persistent L3 accumulator

    auto l2chunk = [&](int c, int buf) {
        f32x16 e0 = {}, e1 = {};                 // 2-chain ILP
        const __bf16* ap = h1 + arow*320;
        const int nt = c*4 + nw;
        const __bf16* bp = W2B + ((nt*20)*64 + lane)*8;
        #pragma unroll
        for (int ks = 0; ks < 20; ks += 2) {
            const int k0a = ks*16 + l5*8;
            const int k0b = k0a + 16;
            bf16x8 afa = ld8(ap + (((k0a >> 3) ^ rsw) << 3));
            bf16x8 afb = ld8(ap + (((k0b >> 3) ^ rsw) << 3));
            bf16x8 ba = ld8(bp + ks*512);
            bf16x8 bb = ld8(bp + ks*512 + 512);
            e0 = mfma32(afa, ba, e0);
            e1 = mfma32(afb, bb, e1);
        }
        __bf16* dst = h2c + buf*8192;
        const int col = nw*32 + l31;             // 0..127 within chunk
        const float bb2 = B2[c*128 + col];
        #pragma unroll
        for (int reg = 0; reg < 16; reg++) {
            const int rl = mw*32 + (reg & 3) + 8*(reg >> 2) + 4*l5;
            float v = e0[reg] + e1[reg] + bb2;
            v = v > 0.0f ? v : 0.01f*v;
            dst[rl*128 + swcol<7>(rl, col)] = (__bf16)v;
        }
    };
    auto l3chunk = [&](int c) {
        const __bf16* src = h2c + (c & 1)*8192 + arow*128;
        const __bf16* bp = W3B + ((nw*40 + c*8)*64 + lane)*8;
        #pragma unroll
        for (int ks = 0; ks < 8; ks++) {
            const int k0 = ks*16 + l5*8;
            bf16x8 af = ld8(src + (((k0 >> 3) ^ rsw) << 3));
            bf16x8 bf = ld8(bp + ks*512);
            acc3 = mfma32(af, bf, acc3);
        }
    };

    l2chunk(0, 0);
    __syncthreads();
    for (int c = 0; c < 5; c++) {
        l3chunk(c);
        if (c < 4) l2chunk(c + 1, (c + 1) & 1);
        __syncthreads();
    }

    // L3 epilogue: bias+relu -> h3 (h1 fully dead after l2chunk(4))
    {
        const int col = nw*32 + l31;
        const float bb3 = B3[col];
        #pragma unroll
        for (int reg = 0; reg < 16; reg++) {
            const int rl = mw*32 + (reg & 3) + 8*(reg >> 2) + 4*l5;
            float v = acc3[reg] + bb3;
            v = v > 0.0f ? v : 0.0f;
            h3[rl*128 + swcol<7>(rl, col)] = (__bf16)v;
        }
    }
    __syncthreads();

    // L4: 16 valid cols; waves 0..3 take one 16-row m-tile each (16x16 path)
    if (wave < 4) {
        f32x4 a4 = {0.0f, 0.0f, 0.0f, 0.0f};
        #pragma unroll
        for (int ks = 0; ks < 4; ks++) {
            const int k0 = ks*32 + lg*8;
            bf16x8 bfv = ld8(W4B + lr*128 + k0);
            const int ar = wave*16 + lr;
            bf16x8 af = ld8(h3 + ar*128 + (k0 ^ ((ar & 7) << 3)));
            a4 = mfma16(af, bfv, a4);
        }
        #pragma unroll
        for (int r = 0; r < 4; r++) {
            const int row = wave*16 + lg*4 + r;
            float v = a4[r] + B4[lr];
            v = v > 0.0f ? v : 0.01f*v;
            t1s[row*17 + lr] = v;
        }
    }
    __syncthreads();

    // normalize rows -> T1N [32]-padded bf16
    if (tid < 64) {
        float s = 0.0f, v[13];
        #pragma unroll
        for (int k = 0; k < 13; k++) { v[k] = t1s[tid*17 + k]; s += v[k]*v[k]; }
        const float inv = 1.0f / fmaxf(sqrtf(s), 1e-8f);
        __bf16 o[32];
        #pragma unroll
        for (int k = 0; k < 13; k++) o[k] = (__bf16)(v[k] * inv);
        #pragma unroll
        for (int k = 13; k < 32; k++) o[k] = (__bf16)0.0f;
        bf16x8* dst = reinterpret_cast<bf16x8*>(T1N + (size_t)(bm0 + tid)*32);
        const bf16x8* src = reinterpret_cast<const bf16x8*>(o);
        #pragma unroll
        for (int i = 0; i < 4; i++) dst[i] = src[i];
    }
}

// ---------------------------------------------------------------------------
// sim: 32x32 tiles, 64-way m-split (grid 1024 -> 16 waves/CU). Per step:
// 2 m-tiles, running max via fmax(fmax) -> v_max3 fusion.
// ---------------------------------------------------------------------------
__global__ __launch_bounds__(256) void sim_kernel(const char* __restrict__ ws_c,
                                                  float* __restrict__ part) {
    const char* ws = ws_c;
    const __bf16* T1N = (const __bf16*)(ws + OFF_T1N);
    const __bf16* T2N = (const __bf16*)(ws + OFF_T2N);
    const int wave = threadIdx.x >> 6, lane = threadIdx.x & 63;
    const int l31 = lane & 31, l5 = lane >> 5;
    const int bgroup = blockIdx.x & 15, ms = blockIdx.x >> 4;   // 16 x 64 grid
    const int b0 = (bgroup*4 + wave) * 32;

    const bf16x8 af0 = ld8(T2N + (b0 + l31)*32 + l5*8);
    const bf16x8 af1 = ld8(T2N + (b0 + l31)*32 + 16 + l5*8);
    const f32x16 zero = {};
    f32x16 mx;
    #pragma unroll
    for (int r = 0; r < 16; r++) mx[r] = -3.0e38f;

    // 2048 m-tiles, stride 64: 32 tiles/wave, 2 per step
    #pragma unroll 2
    for (int mt = ms; mt < 2048; mt += 128) {
        const __bf16* p0 = T1N + ((size_t)mt*32 + l31)*32 + l5*8;
        const __bf16* p1 = T1N + ((size_t)(mt + 64)*32 + l31)*32 + l5*8;
        bf16x8 b00 = ld8(p0);
        bf16x8 b01 = ld8(p0 + 16);
        bf16x8 b10 = ld8(p1);
        bf16x8 b11 = ld8(p1 + 16);
        f32x16 d0 = mfma32(af1, b01, mfma32(af0, b00, zero));
        f32x16 d1 = mfma32(af1, b11, mfma32(af0, b10, zero));
        #pragma unroll
        for (int r = 0; r < 16; r++)
            mx[r] = fmaxf(mx[r], fmaxf(d0[r], d1[r]));   // -> v_max3_f32
    }
    #pragma unroll
    for (int off = 1; off <= 16; off <<= 1) {
        #pragma unroll
        for (int r = 0; r < 16; r++) mx[r] = fmaxf(mx[r], __shfl_xor(mx[r], off));
    }
    if (l31 == 0) {
        #pragma unroll
        for (int reg = 0; reg < 16; reg++)
            part[ms*2048 + b0 + (reg & 3) + 8*(reg >> 2) + 4*l5] = mx[reg];
    }
}

__global__ void reduce_kernel(const float* __restrict__ part, float* __restrict__ out) {
    int b = blockIdx.x*256 + threadIdx.x;
    if (b < 2048) {
        float m = part[b];
        #pragma unroll
        for (int ms = 1; ms < 64; ms++) m = fmaxf(m, part[ms*2048 + b]);
        out[b] = 23.0f * m;
    }
}

// ---------------------------------------------------------------------------
extern "C" void kernel_launch(void* const* d_in, const int* in_sizes, int n_in,
                              void* d_out, int out_size, void* d_ws, size_t ws_size,
                              hipStream_t stream) {
    const float* memory = (const float*)d_in[0];
    const float* value  = (const float*)d_in[1];
    const float* W1 = (const float*)d_in[2]; const float* b1 = (const float*)d_in[3];
    const float* W2 = (const float*)d_in[4]; const float* b2 = (const float*)d_in[5];
    const float* W3 = (const float*)d_in[6]; const float* b3 = (const float*)d_in[7];
    const float* W4 = (const float*)d_in[8]; const float* b4 = (const float*)d_in[9];
    char* ws = (char*)d_ws;
    float* part = (float*)(ws + OFF_PART);
    float* out = (float*)d_out;

    prep_kernel<<<1189, 256, 0, stream>>>(W1, b1, W2, b2, W3, b3, W4, b4, value, ws);
    mlp_kernel<<<1024, 512, 0, stream>>>(memory, ws);
    sim_kernel<<<1024, 256, 0, stream>>>(ws, part);
    reduce_kernel<<<8, 256, 0, stream>>>(part, out);
}